// Round 4
// baseline (642.058 us; speedup 1.0000x reference)
//
#include <hip/hip_runtime.h>

typedef unsigned short u16;
typedef unsigned int u32;
typedef __bf16 bf16x8 __attribute__((ext_vector_type(8)));
typedef u16 u16x8 __attribute__((ext_vector_type(8)));
typedef float f32x4 __attribute__((ext_vector_type(4)));

#define MFMA(a, b, c) __builtin_amdgcn_mfma_f32_16x16x32_bf16(a, b, c, 0, 0, 0)

__device__ __forceinline__ u16 f2bf(float x) {
    u32 u = __builtin_bit_cast(u32, x);
    u32 r = (u + 0x7FFFu + ((u >> 16) & 1u)) >> 16;
    return (u16)r;
}
__device__ __forceinline__ float bf2f(u16 h) {
    u32 u = ((u32)h) << 16;
    return __builtin_bit_cast(float, u);
}
__device__ __forceinline__ float silu_f(float x) {
    return x * __builtin_amdgcn_rcpf(1.f + __expf(-x));
}
__device__ __forceinline__ bf16x8 ldfrag(const u16* p) {
    return __builtin_bit_cast(bf16x8, *(const u16x8*)p);
}

// ---------------- h -> bf16 table (only when ws has room) ----------------
__global__ void k_prep(const float* __restrict__ nf, u16* __restrict__ hbf, int NN) {
    int idx = blockIdx.x * 256 + threadIdx.x;
    int i = idx >> 4, p = idx & 15;
    if (i >= NN) return;
    const float* src = nf + (size_t)i * 131 + 3 + p * 8;
    u16x8 v;
#pragma unroll
    for (int j = 0; j < 8; ++j) v[j] = f2bf(src[j]);
    *(u16x8*)(hbf + (size_t)i * 128 + p * 8) = v;
}

// ---------------- degree histogram ----------------
__global__ void k_hist(const int* __restrict__ first, int* __restrict__ cnt, int NE) {
    int e = blockIdx.x * 256 + threadIdx.x;
    if (e < NE) atomicAdd(&cnt[first[e]], 1);
}

// ---------------- counting-sort: scan + scatter ----------------
__global__ void k_scanA(const int* __restrict__ cnt, int* __restrict__ cursor,
                        int* __restrict__ bsum, int NN) {
    __shared__ int wsum[4];
    const int t = threadIdx.x;
    const int base = blockIdx.x * 1024 + t * 4;
    int v0 = base + 0 < NN ? cnt[base + 0] : 0;
    int v1 = base + 1 < NN ? cnt[base + 1] : 0;
    int v2 = base + 2 < NN ? cnt[base + 2] : 0;
    int v3 = base + 3 < NN ? cnt[base + 3] : 0;
    const int s = v0 + v1 + v2 + v3;
    const int lane = t & 63, w = t >> 6;
    int x = s;
#pragma unroll
    for (int d = 1; d < 64; d <<= 1) {
        int y = __shfl_up(x, d);
        if (lane >= d) x += y;
    }
    if (lane == 63) wsum[w] = x;
    __syncthreads();
    int wbase = 0;
    for (int k = 0; k < w; ++k) wbase += wsum[k];
    int run = wbase + x - s;  // exclusive prefix of this thread's 4 items
    if (base + 0 < NN) cursor[base + 0] = run; run += v0;
    if (base + 1 < NN) cursor[base + 1] = run; run += v1;
    if (base + 2 < NN) cursor[base + 2] = run; run += v2;
    if (base + 3 < NN) cursor[base + 3] = run;
    if (t == 255) bsum[blockIdx.x] = wbase + x;
}

__global__ void k_scanB(int* bsum, int NB) {
    if (threadIdx.x == 0 && blockIdx.x == 0) {
        int run = 0;
        for (int b = 0; b < NB; ++b) { int t = bsum[b]; bsum[b] = run; run += t; }
    }
}

__global__ void k_scanC(int* __restrict__ cursor, const int* __restrict__ bsum, int NN) {
    int i = blockIdx.x * 256 + threadIdx.x;
    if (i < NN) cursor[i] += bsum[i >> 10];
}

__global__ void k_scatter(const int* __restrict__ first, const int* __restrict__ second,
                          int* __restrict__ cursor, int4* __restrict__ sorted, int NE) {
    int e = blockIdx.x * 256 + threadIdx.x;
    if (e < NE) {
        int f = first[e];
        int pos = atomicAdd(&cursor[f], 1);
        sorted[pos] = make_int4(f, second[e], e, 0);
    }
}

// ---------------- sorted edge kernel: 2-wave blocks, 32-edge tiles ----------------
// Wave w owns output cols [w*64, w*64+64). Per-wave weights in registers (208 VGPR),
// so VGPR~256 -> 8 waves/CU = 4 independent blocks/CU (LDS 38KB/block).
// X = [h_f|h_s|dist2|ef|pad->288] bf16 stride 296; m1 overlays X; m2 in f32 LDS.
// nbr/coord sums via in-tile segmented reduction over sorted `first`.
template <int USE_HBF>
__global__ __launch_bounds__(128, 2) void k_edge_s(
    const u16* __restrict__ hbf, const float* __restrict__ nf,
    const int4* __restrict__ sorted, const float* __restrict__ ef,
    const float* __restrict__ We1, const float* __restrict__ be1,
    const float* __restrict__ We2, const float* __restrict__ be2,
    const float* __restrict__ Wc, const float* __restrict__ bc,
    float* __restrict__ out, int NE, int ntiles) {
    __shared__ u16 Xs[32 * 296];       // 18944 B (m1 [32][136] overlays)
    __shared__ float M2f[32 * 132];    // 16896 B
    __shared__ float cds[32][4];
    __shared__ int fidxs[32];
    __shared__ float be1s[128], be2s[128], Wcs[128];
    __shared__ float bcs;

    const int tid = threadIdx.x;
    const int lane = tid & 63;
    const int wv = tid >> 6;  // 0/1 : column half
    const int lhi = lane >> 4, llo = lane & 15;
    const f32x4 fzero = {0.f, 0.f, 0.f, 0.f};

    be1s[tid] = be1[tid]; be2s[tid] = be2[tid]; Wcs[tid] = Wc[tid];
    if (tid == 0) bcs = bc[0];

    // --- per-wave weight fragments (cols wv*64 .. +63) ---
    bf16x8 w1f[4][9];
    bf16x8 w2f[4][4];
#pragma unroll
    for (int ni = 0; ni < 4; ++ni) {
        const int c = wv * 64 + ni * 16 + llo;
#pragma unroll
        for (int t = 0; t < 9; ++t) {
            u16x8 tmp;
#pragma unroll
            for (int j = 0; j < 8; ++j) {
                int k = t * 32 + lhi * 8 + j;
                float v = (k < 273) ? We1[(size_t)k * 128 + c] : 0.f;
                tmp[j] = f2bf(v);
            }
            w1f[ni][t] = __builtin_bit_cast(bf16x8, tmp);
        }
#pragma unroll
        for (int t = 0; t < 4; ++t) {
            u16x8 tmp;
#pragma unroll
            for (int j = 0; j < 8; ++j) {
                int k = t * 32 + lhi * 8 + j;
                tmp[j] = f2bf(We2[(size_t)k * 128 + c]);
            }
            w2f[ni][t] = __builtin_bit_cast(bf16x8, tmp);
        }
    }

    // contiguous tile chunk per block (h_f locality from sort order)
    const int cpb = (ntiles + gridDim.x - 1) / gridDim.x;
    const int t0 = blockIdx.x * cpb;
    const int t1 = min(t0 + cpb, ntiles);

    for (int tile = t0; tile < t1; ++tile) {
        const int e0 = tile * 32;
        __syncthreads();  // (1) LDS reuse safety (prev seg-reduce done)
        // ---- stage X: 4 threads per edge ----
        {
            const int el = tid >> 2, p = tid & 3;
            const int r = e0 + el;
            if (r < NE) {
                const int4 srec = sorted[r];
                const int f = srec.x, s = srec.y, e = srec.z;
                if (USE_HBF) {
                    const uint4* hf = (const uint4*)(hbf + (size_t)f * 128);
                    const uint4* hs = (const uint4*)(hbf + (size_t)s * 128);
                    uint4* df = (uint4*)(Xs + el * 296 + p * 32);
                    df[0] = hf[p * 4 + 0]; df[1] = hf[p * 4 + 1];
                    df[2] = hf[p * 4 + 2]; df[3] = hf[p * 4 + 3];
                    uint4* ds2 = (uint4*)(Xs + el * 296 + 128 + p * 32);
                    ds2[0] = hs[p * 4 + 0]; ds2[1] = hs[p * 4 + 1];
                    ds2[2] = hs[p * 4 + 2]; ds2[3] = hs[p * 4 + 3];
                } else {
                    const float* src = (p < 2) ? (nf + (size_t)f * 131 + 3 + p * 64)
                                               : (nf + (size_t)s * 131 + 3 + (p - 2) * 64);
                    u16* dst = Xs + el * 296 + p * 64;
#pragma unroll
                    for (int q = 0; q < 64; q += 8) {
                        u16x8 v;
#pragma unroll
                        for (int j = 0; j < 8; ++j) v[j] = f2bf(src[q + j]);
                        *(u16x8*)(dst + q) = v;
                    }
                }
                if (p == 0) {
                    const float* ep = ef + (size_t)e * 16;
                    u16* xr = Xs + el * 296;
#pragma unroll
                    for (int j = 0; j < 16; ++j) xr[257 + j] = f2bf(ep[j]);
                } else if (p == 1) {
                    float ax = nf[(size_t)f * 131 + 0], ay = nf[(size_t)f * 131 + 1], az = nf[(size_t)f * 131 + 2];
                    float bx = nf[(size_t)s * 131 + 0], by = nf[(size_t)s * 131 + 1], bz = nf[(size_t)s * 131 + 2];
                    float dx = ax - bx, dy = ay - by, dz = az - bz;
                    cds[el][0] = dx; cds[el][1] = dy; cds[el][2] = dz;
                    Xs[el * 296 + 256] = f2bf(dx * dx + dy * dy + dz * dz);
                    fidxs[el] = f;
                } else if (p == 2) {
                    u16* xr = Xs + el * 296;
#pragma unroll
                    for (int j = 273; j < 288; ++j) xr[j] = 0;
                }
            } else {
                u16* xr = Xs + el * 296;
#pragma unroll
                for (int j = 0; j < 72; ++j) xr[p * 72 + j] = 0;
                if (p == 1) { fidxs[el] = -1; cds[el][0] = cds[el][1] = cds[el][2] = 0.f; }
            }
        }
        __syncthreads();  // (2) X staged
        // ---- MLP1: X(32x288) @ We1[:, wv half] ----
        f32x4 acc[2][4];
#pragma unroll
        for (int mi = 0; mi < 2; ++mi)
#pragma unroll
            for (int ni = 0; ni < 4; ++ni) acc[mi][ni] = fzero;
        {
            const int arow = llo * 296 + lhi * 8;
            __builtin_amdgcn_s_setprio(1);
#pragma unroll
            for (int t = 0; t < 9; ++t) {
                bf16x8 a0 = ldfrag(Xs + arow + t * 32);
                bf16x8 a1 = ldfrag(Xs + arow + 16 * 296 + t * 32);
#pragma unroll
                for (int ni = 0; ni < 4; ++ni) {
                    acc[0][ni] = MFMA(a0, w1f[ni][t], acc[0][ni]);
                    acc[1][ni] = MFMA(a1, w1f[ni][t], acc[1][ni]);
                }
            }
            __builtin_amdgcn_s_setprio(0);
        }
        __syncthreads();  // (3) X consumed by both waves
        // ---- bias + silu -> m1 (bf16, [32][136], overlays X) ----
        u16* ms = Xs;
#pragma unroll
        for (int mi = 0; mi < 2; ++mi) {
#pragma unroll
            for (int ni = 0; ni < 4; ++ni) {
                const int col = wv * 64 + ni * 16 + llo;
                const float b = be1s[col];
#pragma unroll
                for (int r = 0; r < 4; ++r) {
                    const int row = mi * 16 + lhi * 4 + r;
                    ms[row * 136 + col] = f2bf(silu_f(acc[mi][ni][r] + b));
                }
            }
        }
        __syncthreads();  // (4) m1 complete (both col halves)
        // ---- MLP2: m1(32x128) @ We2[:, wv half] ----
        f32x4 acc2[2][4];
#pragma unroll
        for (int mi = 0; mi < 2; ++mi)
#pragma unroll
            for (int ni = 0; ni < 4; ++ni) acc2[mi][ni] = fzero;
        {
            const int arow = llo * 136 + lhi * 8;
            __builtin_amdgcn_s_setprio(1);
#pragma unroll
            for (int t = 0; t < 4; ++t) {
                bf16x8 a0 = ldfrag(ms + arow + t * 32);
                bf16x8 a1 = ldfrag(ms + arow + 16 * 136 + t * 32);
#pragma unroll
                for (int ni = 0; ni < 4; ++ni) {
                    acc2[0][ni] = MFMA(a0, w2f[ni][t], acc2[0][ni]);
                    acc2[1][ni] = MFMA(a1, w2f[ni][t], acc2[1][ni]);
                }
            }
            __builtin_amdgcn_s_setprio(0);
        }
        // ---- bias + silu -> m2 (f32 LDS, disjoint region) ----
#pragma unroll
        for (int mi = 0; mi < 2; ++mi) {
#pragma unroll
            for (int ni = 0; ni < 4; ++ni) {
                const int col = wv * 64 + ni * 16 + llo;
                const float b = be2s[col];
#pragma unroll
                for (int r = 0; r < 4; ++r) {
                    const int row = mi * 16 + lhi * 4 + r;
                    M2f[row * 132 + col] = silu_f(acc2[mi][ni][r] + b);
                }
            }
        }
        __syncthreads();  // (5) m2 visible
        // ---- coord gate: sc = m2 . Wc + bc; cds *= sc ----
        {
            const int el = tid >> 2, p = tid & 3;
            const float* mrow = M2f + el * 132 + p * 32;
            float dot = 0.f;
#pragma unroll
            for (int i = 0; i < 32; ++i) dot += mrow[i] * Wcs[p * 32 + i];
            dot += __shfl_xor(dot, 1);
            dot += __shfl_xor(dot, 2);
            if (p == 0) {
                const float sc = dot + bcs;
                cds[el][0] *= sc; cds[el][1] *= sc; cds[el][2] *= sc;
            }
        }
        __syncthreads();  // (6) cds scaled
        // ---- segmented reductions (edges sorted by f) ----
        {
            const int col = tid;  // 128 cols
            float sum = 0.f;
            int curf = -2;
            for (int k = 0; k < 32; ++k) {
                const int fr = fidxs[k];
                if (fr != curf) {
                    if (curf >= 0) unsafeAtomicAdd(&out[(size_t)curf * 131 + 3 + col], sum);
                    sum = 0.f; curf = fr;
                }
                sum += M2f[k * 132 + col];
            }
            if (curf >= 0) unsafeAtomicAdd(&out[(size_t)curf * 131 + 3 + col], sum);
        }
        if (tid < 48) {
            const int c = tid % 3;
            const int r0 = (tid / 3) * 2;  // 16 groups x 2 rows
            float sum = 0.f;
            int curf = -2;
#pragma unroll
            for (int k = 0; k < 2; ++k) {
                const int rr = r0 + k;
                const int fr = fidxs[rr];
                if (fr != curf) {
                    if (curf >= 0) unsafeAtomicAdd(&out[(size_t)curf * 131 + c], sum);
                    sum = 0.f; curf = fr;
                }
                sum += cds[rr][c];
            }
            if (curf >= 0) unsafeAtomicAdd(&out[(size_t)curf * 131 + c], sum);
        }
    }
}

// ---------------- unsorted edge kernel (ws fallback, 4-wave) ----------------
template <int USE_HBF>
__global__ __launch_bounds__(256, 1) void k_edge_u(
    const u16* __restrict__ hbf, const float* __restrict__ nf,
    const int* __restrict__ first, const int* __restrict__ second,
    const float* __restrict__ ef,
    const float* __restrict__ We1, const float* __restrict__ be1,
    const float* __restrict__ We2, const float* __restrict__ be2,
    const float* __restrict__ Wc, const float* __restrict__ bc,
    float* __restrict__ out,
    int NE, int ntiles) {
    __shared__ u16 Xs[64 * 296];
    __shared__ float cds[64][4];
    __shared__ int fidxs[64];
    __shared__ float be1s[128], be2s[128], Wcs[128];
    __shared__ float bcs;

    const int tid = threadIdx.x;
    const int lane = tid & 63;
    const int wid = tid >> 6;
    const int wr = wid >> 1, wcn = wid & 1;
    const int lhi = lane >> 4, llo = lane & 15;
    const f32x4 fzero = {0.f, 0.f, 0.f, 0.f};

    if (tid < 128) { be1s[tid] = be1[tid]; be2s[tid] = be2[tid]; Wcs[tid] = Wc[tid]; }
    if (tid == 0) bcs = bc[0];

    bf16x8 w1f[4][9];
    bf16x8 w2f[4][4];
#pragma unroll
    for (int ni = 0; ni < 4; ++ni) {
        const int c = wcn * 64 + ni * 16 + llo;
#pragma unroll
        for (int t = 0; t < 9; ++t) {
            u16x8 tmp;
#pragma unroll
            for (int j = 0; j < 8; ++j) {
                int k = t * 32 + lhi * 8 + j;
                float v = (k < 273) ? We1[(size_t)k * 128 + c] : 0.f;
                tmp[j] = f2bf(v);
            }
            w1f[ni][t] = __builtin_bit_cast(bf16x8, tmp);
        }
#pragma unroll
        for (int t = 0; t < 4; ++t) {
            u16x8 tmp;
#pragma unroll
            for (int j = 0; j < 8; ++j) {
                int k = t * 32 + lhi * 8 + j;
                tmp[j] = f2bf(We2[(size_t)k * 128 + c]);
            }
            w2f[ni][t] = __builtin_bit_cast(bf16x8, tmp);
        }
    }

    for (int tile = blockIdx.x; tile < ntiles; tile += gridDim.x) {
        const int e0 = tile * 64;
        __syncthreads();
        {
            const int el = tid >> 2, p = tid & 3;
            const int e = e0 + el;
            if (e < NE) {
                const int f = first[e], s = second[e];
                if (USE_HBF) {
                    const uint4* hf = (const uint4*)(hbf + (size_t)f * 128);
                    const uint4* hs = (const uint4*)(hbf + (size_t)s * 128);
                    uint4* df = (uint4*)(Xs + el * 296 + p * 32);
                    df[0] = hf[p * 4 + 0]; df[1] = hf[p * 4 + 1];
                    df[2] = hf[p * 4 + 2]; df[3] = hf[p * 4 + 3];
                    uint4* ds2 = (uint4*)(Xs + el * 296 + 128 + p * 32);
                    ds2[0] = hs[p * 4 + 0]; ds2[1] = hs[p * 4 + 1];
                    ds2[2] = hs[p * 4 + 2]; ds2[3] = hs[p * 4 + 3];
                } else {
                    const float* src = (p < 2) ? (nf + (size_t)f * 131 + 3 + p * 64)
                                               : (nf + (size_t)s * 131 + 3 + (p - 2) * 64);
                    u16* dst = Xs + el * 296 + p * 64;
#pragma unroll
                    for (int q = 0; q < 64; q += 8) {
                        u16x8 v;
#pragma unroll
                        for (int j = 0; j < 8; ++j) v[j] = f2bf(src[q + j]);
                        *(u16x8*)(dst + q) = v;
                    }
                }
                if (p == 0) {
                    const float* ep = ef + (size_t)e * 16;
                    u16* xr = Xs + el * 296;
#pragma unroll
                    for (int j = 0; j < 16; ++j) xr[257 + j] = f2bf(ep[j]);
                } else if (p == 1) {
                    float ax = nf[(size_t)f * 131 + 0], ay = nf[(size_t)f * 131 + 1], az = nf[(size_t)f * 131 + 2];
                    float bx = nf[(size_t)s * 131 + 0], by = nf[(size_t)s * 131 + 1], bz = nf[(size_t)s * 131 + 2];
                    float dx = ax - bx, dy = ay - by, dz = az - bz;
                    cds[el][0] = dx; cds[el][1] = dy; cds[el][2] = dz;
                    Xs[el * 296 + 256] = f2bf(dx * dx + dy * dy + dz * dz);
                    fidxs[el] = f;
                } else if (p == 2) {
                    u16* xr = Xs + el * 296;
#pragma unroll
                    for (int j = 273; j < 288; ++j) xr[j] = 0;
                }
            } else {
                u16* xr = Xs + el * 296;
#pragma unroll
                for (int j = 0; j < 72; ++j) xr[p * 72 + j] = 0;
                if (p == 1) { fidxs[el] = -1; cds[el][0] = cds[el][1] = cds[el][2] = 0.f; }
            }
        }
        __syncthreads();
        f32x4 acc[2][4];
#pragma unroll
        for (int mi = 0; mi < 2; ++mi)
#pragma unroll
            for (int ni = 0; ni < 4; ++ni) acc[mi][ni] = fzero;
        {
            const int arow = (wr * 32 + llo) * 296 + lhi * 8;
#pragma unroll
            for (int t = 0; t < 9; ++t) {
                bf16x8 a0 = ldfrag(Xs + arow + t * 32);
                bf16x8 a1 = ldfrag(Xs + arow + 16 * 296 + t * 32);
#pragma unroll
                for (int ni = 0; ni < 4; ++ni) {
                    acc[0][ni] = MFMA(a0, w1f[ni][t], acc[0][ni]);
                    acc[1][ni] = MFMA(a1, w1f[ni][t], acc[1][ni]);
                }
            }
        }
        __syncthreads();
        u16* ms = Xs;
#pragma unroll
        for (int mi = 0; mi < 2; ++mi) {
#pragma unroll
            for (int ni = 0; ni < 4; ++ni) {
                const int col = wcn * 64 + ni * 16 + llo;
                const float b = be1s[col];
#pragma unroll
                for (int r = 0; r < 4; ++r) {
                    const int row = wr * 32 + mi * 16 + lhi * 4 + r;
                    ms[row * 136 + col] = f2bf(silu_f(acc[mi][ni][r] + b));
                }
            }
        }
        __syncthreads();
        f32x4 acc2[2][4];
#pragma unroll
        for (int mi = 0; mi < 2; ++mi)
#pragma unroll
            for (int ni = 0; ni < 4; ++ni) acc2[mi][ni] = fzero;
        {
            const int arow = (wr * 32 + llo) * 136 + lhi * 8;
#pragma unroll
            for (int t = 0; t < 4; ++t) {
                bf16x8 a0 = ldfrag(ms + arow + t * 32);
                bf16x8 a1 = ldfrag(ms + arow + 16 * 136 + t * 32);
#pragma unroll
                for (int ni = 0; ni < 4; ++ni) {
                    acc2[0][ni] = MFMA(a0, w2f[ni][t], acc2[0][ni]);
                    acc2[1][ni] = MFMA(a1, w2f[ni][t], acc2[1][ni]);
                }
            }
        }
        __syncthreads();
#pragma unroll
        for (int mi = 0; mi < 2; ++mi) {
#pragma unroll
            for (int ni = 0; ni < 4; ++ni) {
                const int col = wcn * 64 + ni * 16 + llo;
                const float b = be2s[col];
#pragma unroll
                for (int r = 0; r < 4; ++r) {
                    const int row = wr * 32 + mi * 16 + lhi * 4 + r;
                    float v = silu_f(acc2[mi][ni][r] + b);
                    acc2[mi][ni][r] = v;
                    ms[row * 136 + col] = f2bf(v);
                }
            }
        }
#pragma unroll
        for (int mi = 0; mi < 2; ++mi) {
#pragma unroll
            for (int ni = 0; ni < 4; ++ni) {
                const int col = wcn * 64 + ni * 16 + llo;
#pragma unroll
                for (int r = 0; r < 4; ++r) {
                    const int row = wr * 32 + mi * 16 + lhi * 4 + r;
                    const int f = fidxs[row];
                    if (f >= 0) unsafeAtomicAdd(&out[(size_t)f * 131 + 3 + col], acc2[mi][ni][r]);
                }
            }
        }
        __syncthreads();
        {
            const int el = tid >> 2, p = tid & 3;
            const u32* mrow = (const u32*)(ms + el * 136 + p * 32);
            float dot = 0.f;
#pragma unroll
            for (int i = 0; i < 16; ++i) {
                u32 w = mrow[i];
                dot += bf2f((u16)(w & 0xffffu)) * Wcs[p * 32 + 2 * i];
                dot += bf2f((u16)(w >> 16)) * Wcs[p * 32 + 2 * i + 1];
            }
            dot += __shfl_xor(dot, 1);
            dot += __shfl_xor(dot, 2);
            if (p == 0) {
                const int f = fidxs[el];
                if (f >= 0) {
                    const float sc = dot + bcs;
                    unsafeAtomicAdd(&out[(size_t)f * 131 + 0], cds[el][0] * sc);
                    unsafeAtomicAdd(&out[(size_t)f * 131 + 1], cds[el][1] * sc);
                    unsafeAtomicAdd(&out[(size_t)f * 131 + 2], cds[el][2] * sc);
                }
            }
        }
    }
}

// ---------------- node kernel: 2-wave blocks, 32-node tiles ----------------
template <int USE_HBF>
__global__ __launch_bounds__(128, 2) void k_node(
    const u16* __restrict__ hbf, const float* __restrict__ nf,
    const int* __restrict__ cnt,
    const float* __restrict__ Wn1, const float* __restrict__ bn1,
    const float* __restrict__ Wn2, const float* __restrict__ bn2,
    float* __restrict__ out, int NN, int ntiles) {
    __shared__ u16 Xs[32 * 264];   // 16896 B (m1 [32][136] overlays)
    __shared__ float b1s[128], b2s[128];

    const int tid = threadIdx.x;
    const int lane = tid & 63;
    const int wv = tid >> 6;
    const int lhi = lane >> 4, llo = lane & 15;
    const f32x4 fzero = {0.f, 0.f, 0.f, 0.f};

    b1s[tid] = bn1[tid]; b2s[tid] = bn2[tid];

    bf16x8 w1f[4][8];
    bf16x8 w2f[4][4];
#pragma unroll
    for (int ni = 0; ni < 4; ++ni) {
        const int c = wv * 64 + ni * 16 + llo;
#pragma unroll
        for (int t = 0; t < 8; ++t) {
            u16x8 tmp;
#pragma unroll
            for (int j = 0; j < 8; ++j) {
                int k = t * 32 + lhi * 8 + j;
                tmp[j] = f2bf(Wn1[(size_t)k * 128 + c]);
            }
            w1f[ni][t] = __builtin_bit_cast(bf16x8, tmp);
        }
#pragma unroll
        for (int t = 0; t < 4; ++t) {
            u16x8 tmp;
#pragma unroll
            for (int j = 0; j < 8; ++j) {
                int k = t * 32 + lhi * 8 + j;
                tmp[j] = f2bf(Wn2[(size_t)k * 128 + c]);
            }
            w2f[ni][t] = __builtin_bit_cast(bf16x8, tmp);
        }
    }

    const int cpb = (ntiles + gridDim.x - 1) / gridDim.x;
    const int t0 = blockIdx.x * cpb;
    const int t1 = min(t0 + cpb, ntiles);

    for (int tile = t0; tile < t1; ++tile) {
        const int n0 = tile * 32;
        __syncthreads();
        // ---- stage [h | nbr_sum] ----
        {
            const int el = tid >> 2, p = tid & 3;
            const int i = n0 + el;
            if (i < NN) {
                if (USE_HBF) {
                    const uint4* hr = (const uint4*)(hbf + (size_t)i * 128);
                    uint4* d = (uint4*)(Xs + el * 264 + p * 32);
                    d[0] = hr[p * 4 + 0]; d[1] = hr[p * 4 + 1];
                    d[2] = hr[p * 4 + 2]; d[3] = hr[p * 4 + 3];
                } else {
                    const float* src = nf + (size_t)i * 131 + 3 + p * 32;
                    u16* dst = Xs + el * 264 + p * 32;
#pragma unroll
                    for (int q = 0; q < 32; q += 8) {
                        u16x8 v;
#pragma unroll
                        for (int j = 0; j < 8; ++j) v[j] = f2bf(src[q + j]);
                        *(u16x8*)(dst + q) = v;
                    }
                }
                const float* nb = out + (size_t)i * 131 + 3 + p * 32;
                u16* dst = Xs + el * 264 + 128 + p * 32;
#pragma unroll
                for (int q = 0; q < 32; q += 8) {
                    u16x8 v;
#pragma unroll
                    for (int j = 0; j < 8; ++j) v[j] = f2bf(nb[q + j]);
                    *(u16x8*)(dst + q) = v;
                }
            } else {
#pragma unroll
                for (int j = 0; j < 64; ++j) Xs[el * 264 + p * 64 + j] = 0;
            }
        }
        __syncthreads();
        // ---- MLP1: K=256 ----
        f32x4 acc[2][4];
#pragma unroll
        for (int mi = 0; mi < 2; ++mi)
#pragma unroll
            for (int ni = 0; ni < 4; ++ni) acc[mi][ni] = fzero;
        {
            const int arow = llo * 264 + lhi * 8;
            __builtin_amdgcn_s_setprio(1);
#pragma unroll
            for (int t = 0; t < 8; ++t) {
                bf16x8 a0 = ldfrag(Xs + arow + t * 32);
                bf16x8 a1 = ldfrag(Xs + arow + 16 * 264 + t * 32);
#pragma unroll
                for (int ni = 0; ni < 4; ++ni) {
                    acc[0][ni] = MFMA(a0, w1f[ni][t], acc[0][ni]);
                    acc[1][ni] = MFMA(a1, w1f[ni][t], acc[1][ni]);
                }
            }
            __builtin_amdgcn_s_setprio(0);
        }
        __syncthreads();
        // ---- bias + silu -> m1 ----
        u16* ms = Xs;
#pragma unroll
        for (int mi = 0; mi < 2; ++mi) {
#pragma unroll
            for (int ni = 0; ni < 4; ++ni) {
                const int col = wv * 64 + ni * 16 + llo;
                const float b = b1s[col];
#pragma unroll
                for (int r = 0; r < 4; ++r) {
                    const int row = mi * 16 + lhi * 4 + r;
                    ms[row * 136 + col] = f2bf(silu_f(acc[mi][ni][r] + b));
                }
            }
        }
        __syncthreads();
        // ---- MLP2: K=128 ----
        f32x4 acc2[2][4];
#pragma unroll
        for (int mi = 0; mi < 2; ++mi)
#pragma unroll
            for (int ni = 0; ni < 4; ++ni) acc2[mi][ni] = fzero;
        {
            const int arow = llo * 136 + lhi * 8;
            __builtin_amdgcn_s_setprio(1);
#pragma unroll
            for (int t = 0; t < 4; ++t) {
                bf16x8 a0 = ldfrag(ms + arow + t * 32);
                bf16x8 a1 = ldfrag(ms + arow + 16 * 136 + t * 32);
#pragma unroll
                for (int ni = 0; ni < 4; ++ni) {
                    acc2[0][ni] = MFMA(a0, w2f[ni][t], acc2[0][ni]);
                    acc2[1][ni] = MFMA(a1, w2f[ni][t], acc2[1][ni]);
                }
            }
            __builtin_amdgcn_s_setprio(0);
        }
        // ---- store node outputs ----
#pragma unroll
        for (int mi = 0; mi < 2; ++mi) {
#pragma unroll
            for (int ni = 0; ni < 4; ++ni) {
                const int col = wv * 64 + ni * 16 + llo;
                const float b = b2s[col];
#pragma unroll
                for (int r = 0; r < 4; ++r) {
                    const int row = mi * 16 + lhi * 4 + r;
                    const int i = n0 + row;
                    if (i < NN) out[(size_t)i * 131 + 3 + col] = acc2[mi][ni][r] + b;
                }
            }
        }
        // ---- coords epilogue ----
        {
            const int el = tid >> 2, c = tid & 3;
            const int i = n0 + el;
            if (c < 3 && i < NN) {
                float cc = out[(size_t)i * 131 + c];
                out[(size_t)i * 131 + c] =
                    nf[(size_t)i * 131 + c] + cc / fmaxf((float)cnt[i], 1.f);
            }
        }
    }
}

extern "C" void kernel_launch(void* const* d_in, const int* in_sizes, int n_in,
                              void* d_out, int out_size, void* d_ws, size_t ws_size,
                              hipStream_t stream) {
    const float* nf = (const float*)d_in[0];
    const int* ei = (const int*)d_in[1];
    const float* ef = (const float*)d_in[2];
    const float* We1 = (const float*)d_in[3];
    const float* be1 = (const float*)d_in[4];
    const float* We2 = (const float*)d_in[5];
    const float* be2 = (const float*)d_in[6];
    const float* Wc = (const float*)d_in[7];
    const float* bc = (const float*)d_in[8];
    const float* Wn1 = (const float*)d_in[9];
    const float* bn1 = (const float*)d_in[10];
    const float* Wn2 = (const float*)d_in[11];
    const float* bn2 = (const float*)d_in[12];

    const int NN = in_sizes[0] / 131;
    const int NE = in_sizes[2] / 16;
    float* out = (float*)d_out;
    char* ws = (char*)d_ws;

    // ws layout: [cnt][cursor][bsum pad][sorted][hbf]
    const size_t szN = (size_t)NN * 4;
    const size_t o_cnt = 0;
    const size_t o_cur = szN;
    const size_t o_bsum = 2 * szN;
    const size_t o_sorted = (2 * szN + 4096 + 15) & ~(size_t)15;
    const size_t o_hbf_s = o_sorted + (size_t)NE * 16;
    const size_t need_core = o_hbf_s;
    const size_t need_full = o_hbf_s + (size_t)NN * 256;

    hipMemsetAsync(d_out, 0, (size_t)out_size * 4, stream);
    hipMemsetAsync(ws + o_cnt, 0, szN, stream);

    int* cnt = (int*)(ws + o_cnt);
    const int ntiles_n = (NN + 31) / 32;

    if (ws_size >= need_core) {
        int* cursor = (int*)(ws + o_cur);
        int* bsum = (int*)(ws + o_bsum);
        int4* sorted = (int4*)(ws + o_sorted);
        const bool use_hbf = ws_size >= need_full;
        u16* hbf = (u16*)(ws + o_hbf_s);

        if (use_hbf) k_prep<<<(NN * 16 + 255) / 256, 256, 0, stream>>>(nf, hbf, NN);
        k_hist<<<(NE + 255) / 256, 256, 0, stream>>>(ei, cnt, NE);
        const int NB = (NN + 1023) / 1024;
        k_scanA<<<NB, 256, 0, stream>>>(cnt, cursor, bsum, NN);
        k_scanB<<<1, 64, 0, stream>>>(bsum, NB);
        k_scanC<<<(NN + 255) / 256, 256, 0, stream>>>(cursor, bsum, NN);
        k_scatter<<<(NE + 255) / 256, 256, 0, stream>>>(ei, ei + NE, cursor, sorted, NE);

        const int ntiles_e = (NE + 31) / 32;
        if (use_hbf) {
            k_edge_s<1><<<1024, 128, 0, stream>>>(hbf, nf, sorted, ef,
                                                  We1, be1, We2, be2, Wc, bc, out, NE, ntiles_e);
            k_node<1><<<1024, 128, 0, stream>>>(hbf, nf, cnt, Wn1, bn1, Wn2, bn2, out, NN, ntiles_n);
        } else {
            k_edge_s<0><<<1024, 128, 0, stream>>>(hbf, nf, sorted, ef,
                                                  We1, be1, We2, be2, Wc, bc, out, NE, ntiles_e);
            k_node<0><<<1024, 128, 0, stream>>>(hbf, nf, cnt, Wn1, bn1, Wn2, bn2, out, NN, ntiles_n);
        }
    } else {
        // fallback: unsorted path (cnt + optional hbf)
        u16* hbf = (u16*)(ws + szN);
        const bool use_hbf = ws_size >= szN + (size_t)NN * 256;
        if (use_hbf) k_prep<<<(NN * 16 + 255) / 256, 256, 0, stream>>>(nf, hbf, NN);
        k_hist<<<(NE + 255) / 256, 256, 0, stream>>>(ei, cnt, NE);
        const int etiles = (NE + 63) / 64;
        if (use_hbf) {
            k_edge_u<1><<<512, 256, 0, stream>>>(hbf, nf, ei, ei + NE, ef,
                                                 We1, be1, We2, be2, Wc, bc, out, NE, etiles);
            k_node<1><<<1024, 128, 0, stream>>>(hbf, nf, cnt, Wn1, bn1, Wn2, bn2, out, NN, ntiles_n);
        } else {
            k_edge_u<0><<<512, 256, 0, stream>>>(hbf, nf, ei, ei + NE, ef,
                                                 We1, be1, We2, be2, Wc, bc, out, NE, etiles);
            k_node<0><<<1024, 128, 0, stream>>>(hbf, nf, cnt, Wn1, bn1, Wn2, bn2, out, NN, ntiles_n);
        }
    }
}

// Round 5
// 549.259 us; speedup vs baseline: 1.1690x; 1.1690x over previous
//
#include <hip/hip_runtime.h>

typedef unsigned short u16;
typedef unsigned int u32;
typedef __bf16 bf16x8 __attribute__((ext_vector_type(8)));
typedef u16 u16x8 __attribute__((ext_vector_type(8)));
typedef float f32x4 __attribute__((ext_vector_type(4)));

#define MFMA(a, b, c) __builtin_amdgcn_mfma_f32_16x16x32_bf16(a, b, c, 0, 0, 0)

__device__ __forceinline__ u16 f2bf(float x) {
    u32 u = __builtin_bit_cast(u32, x);
    u32 r = (u + 0x7FFFu + ((u >> 16) & 1u)) >> 16;
    return (u16)r;
}
__device__ __forceinline__ float bf2f(u16 h) {
    u32 u = ((u32)h) << 16;
    return __builtin_bit_cast(float, u);
}
__device__ __forceinline__ float silu_f(float x) {
    return x * __builtin_amdgcn_rcpf(1.f + __expf(-x));
}
__device__ __forceinline__ bf16x8 ldfrag(const u16* p) {
    return __builtin_bit_cast(bf16x8, *(const u16x8*)p);
}

// ---------------- h -> bf16 table (only when ws has room) ----------------
__global__ void k_prep(const float* __restrict__ nf, u16* __restrict__ hbf, int NN) {
    int idx = blockIdx.x * 256 + threadIdx.x;
    int i = idx >> 4, p = idx & 15;
    if (i >= NN) return;
    const float* src = nf + (size_t)i * 131 + 3 + p * 8;
    u16x8 v;
#pragma unroll
    for (int j = 0; j < 8; ++j) v[j] = f2bf(src[j]);
    *(u16x8*)(hbf + (size_t)i * 128 + p * 8) = v;
}

// ---------------- degree histogram ----------------
__global__ void k_hist(const int* __restrict__ first, int* __restrict__ cnt, int NE) {
    int e = blockIdx.x * 256 + threadIdx.x;
    if (e < NE) atomicAdd(&cnt[first[e]], 1);
}

// ---------------- counting-sort: scan + scatter ----------------
__global__ void k_scanA(const int* __restrict__ cnt, int* __restrict__ cursor,
                        int* __restrict__ bsum, int NN) {
    __shared__ int wsum[4];
    const int t = threadIdx.x;
    const int base = blockIdx.x * 1024 + t * 4;
    int v0 = base + 0 < NN ? cnt[base + 0] : 0;
    int v1 = base + 1 < NN ? cnt[base + 1] : 0;
    int v2 = base + 2 < NN ? cnt[base + 2] : 0;
    int v3 = base + 3 < NN ? cnt[base + 3] : 0;
    const int s = v0 + v1 + v2 + v3;
    const int lane = t & 63, w = t >> 6;
    int x = s;
#pragma unroll
    for (int d = 1; d < 64; d <<= 1) {
        int y = __shfl_up(x, d);
        if (lane >= d) x += y;
    }
    if (lane == 63) wsum[w] = x;
    __syncthreads();
    int wbase = 0;
    for (int k = 0; k < w; ++k) wbase += wsum[k];
    int run = wbase + x - s;  // exclusive prefix of this thread's 4 items
    if (base + 0 < NN) cursor[base + 0] = run; run += v0;
    if (base + 1 < NN) cursor[base + 1] = run; run += v1;
    if (base + 2 < NN) cursor[base + 2] = run; run += v2;
    if (base + 3 < NN) cursor[base + 3] = run;
    if (t == 255) bsum[blockIdx.x] = wbase + x;
}

__global__ void k_scanB(int* bsum, int NB) {
    if (threadIdx.x == 0 && blockIdx.x == 0) {
        int run = 0;
        for (int b = 0; b < NB; ++b) { int t = bsum[b]; bsum[b] = run; run += t; }
    }
}

__global__ void k_scanC(int* __restrict__ cursor, const int* __restrict__ bsum, int NN) {
    int i = blockIdx.x * 256 + threadIdx.x;
    if (i < NN) cursor[i] += bsum[i >> 10];
}

__global__ void k_scatter(const int* __restrict__ first, const int* __restrict__ second,
                          int* __restrict__ cursor, int4* __restrict__ sorted, int NE) {
    int e = blockIdx.x * 256 + threadIdx.x;
    if (e < NE) {
        int f = first[e];
        int pos = atomicAdd(&cursor[f], 1);
        sorted[pos] = make_int4(f, second[e], e, 0);
    }
}

// ---------------- sorted edge kernel: 2-wave blocks, 32-edge tiles ----------------
// Wave w owns output cols [w*64, w*64+64). Per-wave weights in registers (~208 VGPR).
// __launch_bounds__(128) (NO waves-per-eu arg): empirically this toolchain caps
// VGPR at 256/min_waves_per_eu -- the round-4 (128,2) forced a 128-VGPR cap and
// spilled all weight fragments to scratch (FETCH +224MB, WRITE +141MB). With
// (128): VGPR~256, LDS 38.4KB -> 4 blocks/CU = 4 independent 2-wave pipelines.
// X = [h_f|h_s|dist2|ef|pad->288] bf16 stride 296; m1 overlays X; m2 in f32 LDS.
// nbr/coord sums via in-tile segmented reduction over sorted `first`.
template <int USE_HBF>
__global__ __launch_bounds__(128) void k_edge_s(
    const u16* __restrict__ hbf, const float* __restrict__ nf,
    const int4* __restrict__ sorted, const float* __restrict__ ef,
    const float* __restrict__ We1, const float* __restrict__ be1,
    const float* __restrict__ We2, const float* __restrict__ be2,
    const float* __restrict__ Wc, const float* __restrict__ bc,
    float* __restrict__ out, int NE, int ntiles) {
    __shared__ u16 Xs[32 * 296];       // 18944 B (m1 [32][136] overlays)
    __shared__ float M2f[32 * 132];    // 16896 B
    __shared__ float cds[32][4];
    __shared__ int fidxs[32];
    __shared__ float be1s[128], be2s[128], Wcs[128];
    __shared__ float bcs;

    const int tid = threadIdx.x;
    const int lane = tid & 63;
    const int wv = tid >> 6;  // 0/1 : column half
    const int lhi = lane >> 4, llo = lane & 15;
    const f32x4 fzero = {0.f, 0.f, 0.f, 0.f};

    be1s[tid] = be1[tid]; be2s[tid] = be2[tid]; Wcs[tid] = Wc[tid];
    if (tid == 0) bcs = bc[0];

    // --- per-wave weight fragments (cols wv*64 .. +63) ---
    bf16x8 w1f[4][9];
    bf16x8 w2f[4][4];
#pragma unroll
    for (int ni = 0; ni < 4; ++ni) {
        const int c = wv * 64 + ni * 16 + llo;
#pragma unroll
        for (int t = 0; t < 9; ++t) {
            u16x8 tmp;
#pragma unroll
            for (int j = 0; j < 8; ++j) {
                int k = t * 32 + lhi * 8 + j;
                float v = (k < 273) ? We1[(size_t)k * 128 + c] : 0.f;
                tmp[j] = f2bf(v);
            }
            w1f[ni][t] = __builtin_bit_cast(bf16x8, tmp);
        }
#pragma unroll
        for (int t = 0; t < 4; ++t) {
            u16x8 tmp;
#pragma unroll
            for (int j = 0; j < 8; ++j) {
                int k = t * 32 + lhi * 8 + j;
                tmp[j] = f2bf(We2[(size_t)k * 128 + c]);
            }
            w2f[ni][t] = __builtin_bit_cast(bf16x8, tmp);
        }
    }

    // contiguous tile chunk per block (h_f locality from sort order)
    const int cpb = (ntiles + gridDim.x - 1) / gridDim.x;
    const int t0 = blockIdx.x * cpb;
    const int t1 = min(t0 + cpb, ntiles);

    for (int tile = t0; tile < t1; ++tile) {
        const int e0 = tile * 32;
        __syncthreads();  // (1) LDS reuse safety (prev seg-reduce done)
        // ---- stage X: 4 threads per edge ----
        {
            const int el = tid >> 2, p = tid & 3;
            const int r = e0 + el;
            if (r < NE) {
                const int4 srec = sorted[r];
                const int f = srec.x, s = srec.y, e = srec.z;
                if (USE_HBF) {
                    const uint4* hf = (const uint4*)(hbf + (size_t)f * 128);
                    const uint4* hs = (const uint4*)(hbf + (size_t)s * 128);
                    uint4* df = (uint4*)(Xs + el * 296 + p * 32);
                    df[0] = hf[p * 4 + 0]; df[1] = hf[p * 4 + 1];
                    df[2] = hf[p * 4 + 2]; df[3] = hf[p * 4 + 3];
                    uint4* ds2 = (uint4*)(Xs + el * 296 + 128 + p * 32);
                    ds2[0] = hs[p * 4 + 0]; ds2[1] = hs[p * 4 + 1];
                    ds2[2] = hs[p * 4 + 2]; ds2[3] = hs[p * 4 + 3];
                } else {
                    const float* src = (p < 2) ? (nf + (size_t)f * 131 + 3 + p * 64)
                                               : (nf + (size_t)s * 131 + 3 + (p - 2) * 64);
                    u16* dst = Xs + el * 296 + p * 64;
#pragma unroll
                    for (int q = 0; q < 64; q += 8) {
                        u16x8 v;
#pragma unroll
                        for (int j = 0; j < 8; ++j) v[j] = f2bf(src[q + j]);
                        *(u16x8*)(dst + q) = v;
                    }
                }
                if (p == 0) {
                    const float* ep = ef + (size_t)e * 16;
                    u16* xr = Xs + el * 296;
#pragma unroll
                    for (int j = 0; j < 16; ++j) xr[257 + j] = f2bf(ep[j]);
                } else if (p == 1) {
                    float ax = nf[(size_t)f * 131 + 0], ay = nf[(size_t)f * 131 + 1], az = nf[(size_t)f * 131 + 2];
                    float bx = nf[(size_t)s * 131 + 0], by = nf[(size_t)s * 131 + 1], bz = nf[(size_t)s * 131 + 2];
                    float dx = ax - bx, dy = ay - by, dz = az - bz;
                    cds[el][0] = dx; cds[el][1] = dy; cds[el][2] = dz;
                    Xs[el * 296 + 256] = f2bf(dx * dx + dy * dy + dz * dz);
                    fidxs[el] = f;
                } else if (p == 2) {
                    u16* xr = Xs + el * 296;
#pragma unroll
                    for (int j = 273; j < 288; ++j) xr[j] = 0;
                }
            } else {
                u16* xr = Xs + el * 296;
#pragma unroll
                for (int j = 0; j < 72; ++j) xr[p * 72 + j] = 0;
                if (p == 1) { fidxs[el] = -1; cds[el][0] = cds[el][1] = cds[el][2] = 0.f; }
            }
        }
        __syncthreads();  // (2) X staged
        // ---- MLP1: X(32x288) @ We1[:, wv half] ----
        f32x4 acc[2][4];
#pragma unroll
        for (int mi = 0; mi < 2; ++mi)
#pragma unroll
            for (int ni = 0; ni < 4; ++ni) acc[mi][ni] = fzero;
        {
            const int arow = llo * 296 + lhi * 8;
            __builtin_amdgcn_s_setprio(1);
#pragma unroll
            for (int t = 0; t < 9; ++t) {
                bf16x8 a0 = ldfrag(Xs + arow + t * 32);
                bf16x8 a1 = ldfrag(Xs + arow + 16 * 296 + t * 32);
#pragma unroll
                for (int ni = 0; ni < 4; ++ni) {
                    acc[0][ni] = MFMA(a0, w1f[ni][t], acc[0][ni]);
                    acc[1][ni] = MFMA(a1, w1f[ni][t], acc[1][ni]);
                }
            }
            __builtin_amdgcn_s_setprio(0);
        }
        __syncthreads();  // (3) X consumed by both waves
        // ---- bias + silu -> m1 (bf16, [32][136], overlays X) ----
        u16* ms = Xs;
#pragma unroll
        for (int mi = 0; mi < 2; ++mi) {
#pragma unroll
            for (int ni = 0; ni < 4; ++ni) {
                const int col = wv * 64 + ni * 16 + llo;
                const float b = be1s[col];
#pragma unroll
                for (int r = 0; r < 4; ++r) {
                    const int row = mi * 16 + lhi * 4 + r;
                    ms[row * 136 + col] = f2bf(silu_f(acc[mi][ni][r] + b));
                }
            }
        }
        __syncthreads();  // (4) m1 complete (both col halves)
        // ---- MLP2: m1(32x128) @ We2[:, wv half] ----
        f32x4 acc2[2][4];
#pragma unroll
        for (int mi = 0; mi < 2; ++mi)
#pragma unroll
            for (int ni = 0; ni < 4; ++ni) acc2[mi][ni] = fzero;
        {
            const int arow = llo * 136 + lhi * 8;
            __builtin_amdgcn_s_setprio(1);
#pragma unroll
            for (int t = 0; t < 4; ++t) {
                bf16x8 a0 = ldfrag(ms + arow + t * 32);
                bf16x8 a1 = ldfrag(ms + arow + 16 * 136 + t * 32);
#pragma unroll
                for (int ni = 0; ni < 4; ++ni) {
                    acc2[0][ni] = MFMA(a0, w2f[ni][t], acc2[0][ni]);
                    acc2[1][ni] = MFMA(a1, w2f[ni][t], acc2[1][ni]);
                }
            }
            __builtin_amdgcn_s_setprio(0);
        }
        // ---- bias + silu -> m2 (f32 LDS, disjoint region) ----
#pragma unroll
        for (int mi = 0; mi < 2; ++mi) {
#pragma unroll
            for (int ni = 0; ni < 4; ++ni) {
                const int col = wv * 64 + ni * 16 + llo;
                const float b = be2s[col];
#pragma unroll
                for (int r = 0; r < 4; ++r) {
                    const int row = mi * 16 + lhi * 4 + r;
                    M2f[row * 132 + col] = silu_f(acc2[mi][ni][r] + b);
                }
            }
        }
        __syncthreads();  // (5) m2 visible
        // ---- coord gate: sc = m2 . Wc + bc; cds *= sc ----
        {
            const int el = tid >> 2, p = tid & 3;
            const float* mrow = M2f + el * 132 + p * 32;
            float dot = 0.f;
#pragma unroll
            for (int i = 0; i < 32; ++i) dot += mrow[i] * Wcs[p * 32 + i];
            dot += __shfl_xor(dot, 1);
            dot += __shfl_xor(dot, 2);
            if (p == 0) {
                const float sc = dot + bcs;
                cds[el][0] *= sc; cds[el][1] *= sc; cds[el][2] *= sc;
            }
        }
        __syncthreads();  // (6) cds scaled
        // ---- segmented reductions (edges sorted by f) ----
        {
            const int col = tid;  // 128 cols
            float sum = 0.f;
            int curf = -2;
            for (int k = 0; k < 32; ++k) {
                const int fr = fidxs[k];
                if (fr != curf) {
                    if (curf >= 0) unsafeAtomicAdd(&out[(size_t)curf * 131 + 3 + col], sum);
                    sum = 0.f; curf = fr;
                }
                sum += M2f[k * 132 + col];
            }
            if (curf >= 0) unsafeAtomicAdd(&out[(size_t)curf * 131 + 3 + col], sum);
        }
        if (tid < 48) {
            const int c = tid % 3;
            const int r0 = (tid / 3) * 2;  // 16 groups x 2 rows
            float sum = 0.f;
            int curf = -2;
#pragma unroll
            for (int k = 0; k < 2; ++k) {
                const int rr = r0 + k;
                const int fr = fidxs[rr];
                if (fr != curf) {
                    if (curf >= 0) unsafeAtomicAdd(&out[(size_t)curf * 131 + c], sum);
                    sum = 0.f; curf = fr;
                }
                sum += cds[rr][c];
            }
            if (curf >= 0) unsafeAtomicAdd(&out[(size_t)curf * 131 + c], sum);
        }
    }
}

// ---------------- unsorted edge kernel (ws fallback, 4-wave) ----------------
template <int USE_HBF>
__global__ __launch_bounds__(256, 1) void k_edge_u(
    const u16* __restrict__ hbf, const float* __restrict__ nf,
    const int* __restrict__ first, const int* __restrict__ second,
    const float* __restrict__ ef,
    const float* __restrict__ We1, const float* __restrict__ be1,
    const float* __restrict__ We2, const float* __restrict__ be2,
    const float* __restrict__ Wc, const float* __restrict__ bc,
    float* __restrict__ out,
    int NE, int ntiles) {
    __shared__ u16 Xs[64 * 296];
    __shared__ float cds[64][4];
    __shared__ int fidxs[64];
    __shared__ float be1s[128], be2s[128], Wcs[128];
    __shared__ float bcs;

    const int tid = threadIdx.x;
    const int lane = tid & 63;
    const int wid = tid >> 6;
    const int wr = wid >> 1, wcn = wid & 1;
    const int lhi = lane >> 4, llo = lane & 15;
    const f32x4 fzero = {0.f, 0.f, 0.f, 0.f};

    if (tid < 128) { be1s[tid] = be1[tid]; be2s[tid] = be2[tid]; Wcs[tid] = Wc[tid]; }
    if (tid == 0) bcs = bc[0];

    bf16x8 w1f[4][9];
    bf16x8 w2f[4][4];
#pragma unroll
    for (int ni = 0; ni < 4; ++ni) {
        const int c = wcn * 64 + ni * 16 + llo;
#pragma unroll
        for (int t = 0; t < 9; ++t) {
            u16x8 tmp;
#pragma unroll
            for (int j = 0; j < 8; ++j) {
                int k = t * 32 + lhi * 8 + j;
                float v = (k < 273) ? We1[(size_t)k * 128 + c] : 0.f;
                tmp[j] = f2bf(v);
            }
            w1f[ni][t] = __builtin_bit_cast(bf16x8, tmp);
        }
#pragma unroll
        for (int t = 0; t < 4; ++t) {
            u16x8 tmp;
#pragma unroll
            for (int j = 0; j < 8; ++j) {
                int k = t * 32 + lhi * 8 + j;
                tmp[j] = f2bf(We2[(size_t)k * 128 + c]);
            }
            w2f[ni][t] = __builtin_bit_cast(bf16x8, tmp);
        }
    }

    for (int tile = blockIdx.x; tile < ntiles; tile += gridDim.x) {
        const int e0 = tile * 64;
        __syncthreads();
        {
            const int el = tid >> 2, p = tid & 3;
            const int e = e0 + el;
            if (e < NE) {
                const int f = first[e], s = second[e];
                if (USE_HBF) {
                    const uint4* hf = (const uint4*)(hbf + (size_t)f * 128);
                    const uint4* hs = (const uint4*)(hbf + (size_t)s * 128);
                    uint4* df = (uint4*)(Xs + el * 296 + p * 32);
                    df[0] = hf[p * 4 + 0]; df[1] = hf[p * 4 + 1];
                    df[2] = hf[p * 4 + 2]; df[3] = hf[p * 4 + 3];
                    uint4* ds2 = (uint4*)(Xs + el * 296 + 128 + p * 32);
                    ds2[0] = hs[p * 4 + 0]; ds2[1] = hs[p * 4 + 1];
                    ds2[2] = hs[p * 4 + 2]; ds2[3] = hs[p * 4 + 3];
                } else {
                    const float* src = (p < 2) ? (nf + (size_t)f * 131 + 3 + p * 64)
                                               : (nf + (size_t)s * 131 + 3 + (p - 2) * 64);
                    u16* dst = Xs + el * 296 + p * 64;
#pragma unroll
                    for (int q = 0; q < 64; q += 8) {
                        u16x8 v;
#pragma unroll
                        for (int j = 0; j < 8; ++j) v[j] = f2bf(src[q + j]);
                        *(u16x8*)(dst + q) = v;
                    }
                }
                if (p == 0) {
                    const float* ep = ef + (size_t)e * 16;
                    u16* xr = Xs + el * 296;
#pragma unroll
                    for (int j = 0; j < 16; ++j) xr[257 + j] = f2bf(ep[j]);
                } else if (p == 1) {
                    float ax = nf[(size_t)f * 131 + 0], ay = nf[(size_t)f * 131 + 1], az = nf[(size_t)f * 131 + 2];
                    float bx = nf[(size_t)s * 131 + 0], by = nf[(size_t)s * 131 + 1], bz = nf[(size_t)s * 131 + 2];
                    float dx = ax - bx, dy = ay - by, dz = az - bz;
                    cds[el][0] = dx; cds[el][1] = dy; cds[el][2] = dz;
                    Xs[el * 296 + 256] = f2bf(dx * dx + dy * dy + dz * dz);
                    fidxs[el] = f;
                } else if (p == 2) {
                    u16* xr = Xs + el * 296;
#pragma unroll
                    for (int j = 273; j < 288; ++j) xr[j] = 0;
                }
            } else {
                u16* xr = Xs + el * 296;
#pragma unroll
                for (int j = 0; j < 72; ++j) xr[p * 72 + j] = 0;
                if (p == 1) { fidxs[el] = -1; cds[el][0] = cds[el][1] = cds[el][2] = 0.f; }
            }
        }
        __syncthreads();
        f32x4 acc[2][4];
#pragma unroll
        for (int mi = 0; mi < 2; ++mi)
#pragma unroll
            for (int ni = 0; ni < 4; ++ni) acc[mi][ni] = fzero;
        {
            const int arow = (wr * 32 + llo) * 296 + lhi * 8;
#pragma unroll
            for (int t = 0; t < 9; ++t) {
                bf16x8 a0 = ldfrag(Xs + arow + t * 32);
                bf16x8 a1 = ldfrag(Xs + arow + 16 * 296 + t * 32);
#pragma unroll
                for (int ni = 0; ni < 4; ++ni) {
                    acc[0][ni] = MFMA(a0, w1f[ni][t], acc[0][ni]);
                    acc[1][ni] = MFMA(a1, w1f[ni][t], acc[1][ni]);
                }
            }
        }
        __syncthreads();
        u16* ms = Xs;
#pragma unroll
        for (int mi = 0; mi < 2; ++mi) {
#pragma unroll
            for (int ni = 0; ni < 4; ++ni) {
                const int col = wcn * 64 + ni * 16 + llo;
                const float b = be1s[col];
#pragma unroll
                for (int r = 0; r < 4; ++r) {
                    const int row = wr * 32 + mi * 16 + lhi * 4 + r;
                    ms[row * 136 + col] = f2bf(silu_f(acc[mi][ni][r] + b));
                }
            }
        }
        __syncthreads();
        f32x4 acc2[2][4];
#pragma unroll
        for (int mi = 0; mi < 2; ++mi)
#pragma unroll
            for (int ni = 0; ni < 4; ++ni) acc2[mi][ni] = fzero;
        {
            const int arow = (wr * 32 + llo) * 136 + lhi * 8;
#pragma unroll
            for (int t = 0; t < 4; ++t) {
                bf16x8 a0 = ldfrag(ms + arow + t * 32);
                bf16x8 a1 = ldfrag(ms + arow + 16 * 136 + t * 32);
#pragma unroll
                for (int ni = 0; ni < 4; ++ni) {
                    acc2[0][ni] = MFMA(a0, w2f[ni][t], acc2[0][ni]);
                    acc2[1][ni] = MFMA(a1, w2f[ni][t], acc2[1][ni]);
                }
            }
        }
        __syncthreads();
#pragma unroll
        for (int mi = 0; mi < 2; ++mi) {
#pragma unroll
            for (int ni = 0; ni < 4; ++ni) {
                const int col = wcn * 64 + ni * 16 + llo;
                const float b = be2s[col];
#pragma unroll
                for (int r = 0; r < 4; ++r) {
                    const int row = wr * 32 + mi * 16 + lhi * 4 + r;
                    float v = silu_f(acc2[mi][ni][r] + b);
                    acc2[mi][ni][r] = v;
                    ms[row * 136 + col] = f2bf(v);
                }
            }
        }
#pragma unroll
        for (int mi = 0; mi < 2; ++mi) {
#pragma unroll
            for (int ni = 0; ni < 4; ++ni) {
                const int col = wcn * 64 + ni * 16 + llo;
#pragma unroll
                for (int r = 0; r < 4; ++r) {
                    const int row = wr * 32 + mi * 16 + lhi * 4 + r;
                    const int f = fidxs[row];
                    if (f >= 0) unsafeAtomicAdd(&out[(size_t)f * 131 + 3 + col], acc2[mi][ni][r]);
                }
            }
        }
        __syncthreads();
        {
            const int el = tid >> 2, p = tid & 3;
            const u32* mrow = (const u32*)(ms + el * 136 + p * 32);
            float dot = 0.f;
#pragma unroll
            for (int i = 0; i < 16; ++i) {
                u32 w = mrow[i];
                dot += bf2f((u16)(w & 0xffffu)) * Wcs[p * 32 + 2 * i];
                dot += bf2f((u16)(w >> 16)) * Wcs[p * 32 + 2 * i + 1];
            }
            dot += __shfl_xor(dot, 1);
            dot += __shfl_xor(dot, 2);
            if (p == 0) {
                const int f = fidxs[el];
                if (f >= 0) {
                    const float sc = dot + bcs;
                    unsafeAtomicAdd(&out[(size_t)f * 131 + 0], cds[el][0] * sc);
                    unsafeAtomicAdd(&out[(size_t)f * 131 + 1], cds[el][1] * sc);
                    unsafeAtomicAdd(&out[(size_t)f * 131 + 2], cds[el][2] * sc);
                }
            }
        }
    }
}

// ---------------- node kernel: 2-wave blocks, 32-node tiles ----------------
template <int USE_HBF>
__global__ __launch_bounds__(128) void k_node(
    const u16* __restrict__ hbf, const float* __restrict__ nf,
    const int* __restrict__ cnt,
    const float* __restrict__ Wn1, const float* __restrict__ bn1,
    const float* __restrict__ Wn2, const float* __restrict__ bn2,
    float* __restrict__ out, int NN, int ntiles) {
    __shared__ u16 Xs[32 * 264];   // 16896 B (m1 [32][136] overlays)
    __shared__ float b1s[128], b2s[128];

    const int tid = threadIdx.x;
    const int lane = tid & 63;
    const int wv = tid >> 6;
    const int lhi = lane >> 4, llo = lane & 15;
    const f32x4 fzero = {0.f, 0.f, 0.f, 0.f};

    b1s[tid] = bn1[tid]; b2s[tid] = bn2[tid];

    bf16x8 w1f[4][8];
    bf16x8 w2f[4][4];
#pragma unroll
    for (int ni = 0; ni < 4; ++ni) {
        const int c = wv * 64 + ni * 16 + llo;
#pragma unroll
        for (int t = 0; t < 8; ++t) {
            u16x8 tmp;
#pragma unroll
            for (int j = 0; j < 8; ++j) {
                int k = t * 32 + lhi * 8 + j;
                tmp[j] = f2bf(Wn1[(size_t)k * 128 + c]);
            }
            w1f[ni][t] = __builtin_bit_cast(bf16x8, tmp);
        }
#pragma unroll
        for (int t = 0; t < 4; ++t) {
            u16x8 tmp;
#pragma unroll
            for (int j = 0; j < 8; ++j) {
                int k = t * 32 + lhi * 8 + j;
                tmp[j] = f2bf(Wn2[(size_t)k * 128 + c]);
            }
            w2f[ni][t] = __builtin_bit_cast(bf16x8, tmp);
        }
    }

    const int cpb = (ntiles + gridDim.x - 1) / gridDim.x;
    const int t0 = blockIdx.x * cpb;
    const int t1 = min(t0 + cpb, ntiles);

    for (int tile = t0; tile < t1; ++tile) {
        const int n0 = tile * 32;
        __syncthreads();
        // ---- stage [h | nbr_sum] ----
        {
            const int el = tid >> 2, p = tid & 3;
            const int i = n0 + el;
            if (i < NN) {
                if (USE_HBF) {
                    const uint4* hr = (const uint4*)(hbf + (size_t)i * 128);
                    uint4* d = (uint4*)(Xs + el * 264 + p * 32);
                    d[0] = hr[p * 4 + 0]; d[1] = hr[p * 4 + 1];
                    d[2] = hr[p * 4 + 2]; d[3] = hr[p * 4 + 3];
                } else {
                    const float* src = nf + (size_t)i * 131 + 3 + p * 32;
                    u16* dst = Xs + el * 264 + p * 32;
#pragma unroll
                    for (int q = 0; q < 32; q += 8) {
                        u16x8 v;
#pragma unroll
                        for (int j = 0; j < 8; ++j) v[j] = f2bf(src[q + j]);
                        *(u16x8*)(dst + q) = v;
                    }
                }
                const float* nb = out + (size_t)i * 131 + 3 + p * 32;
                u16* dst = Xs + el * 264 + 128 + p * 32;
#pragma unroll
                for (int q = 0; q < 32; q += 8) {
                    u16x8 v;
#pragma unroll
                    for (int j = 0; j < 8; ++j) v[j] = f2bf(nb[q + j]);
                    *(u16x8*)(dst + q) = v;
                }
            } else {
#pragma unroll
                for (int j = 0; j < 64; ++j) Xs[el * 264 + p * 64 + j] = 0;
            }
        }
        __syncthreads();
        // ---- MLP1: K=256 ----
        f32x4 acc[2][4];
#pragma unroll
        for (int mi = 0; mi < 2; ++mi)
#pragma unroll
            for (int ni = 0; ni < 4; ++ni) acc[mi][ni] = fzero;
        {
            const int arow = llo * 264 + lhi * 8;
            __builtin_amdgcn_s_setprio(1);
#pragma unroll
            for (int t = 0; t < 8; ++t) {
                bf16x8 a0 = ldfrag(Xs + arow + t * 32);
                bf16x8 a1 = ldfrag(Xs + arow + 16 * 264 + t * 32);
#pragma unroll
                for (int ni = 0; ni < 4; ++ni) {
                    acc[0][ni] = MFMA(a0, w1f[ni][t], acc[0][ni]);
                    acc[1][ni] = MFMA(a1, w1f[ni][t], acc[1][ni]);
                }
            }
            __builtin_amdgcn_s_setprio(0);
        }
        __syncthreads();
        // ---- bias + silu -> m1 ----
        u16* ms = Xs;
#pragma unroll
        for (int mi = 0; mi < 2; ++mi) {
#pragma unroll
            for (int ni = 0; ni < 4; ++ni) {
                const int col = wv * 64 + ni * 16 + llo;
                const float b = b1s[col];
#pragma unroll
                for (int r = 0; r < 4; ++r) {
                    const int row = mi * 16 + lhi * 4 + r;
                    ms[row * 136 + col] = f2bf(silu_f(acc[mi][ni][r] + b));
                }
            }
        }
        __syncthreads();
        // ---- MLP2: K=128 ----
        f32x4 acc2[2][4];
#pragma unroll
        for (int mi = 0; mi < 2; ++mi)
#pragma unroll
            for (int ni = 0; ni < 4; ++ni) acc2[mi][ni] = fzero;
        {
            const int arow = llo * 136 + lhi * 8;
            __builtin_amdgcn_s_setprio(1);
#pragma unroll
            for (int t = 0; t < 4; ++t) {
                bf16x8 a0 = ldfrag(ms + arow + t * 32);
                bf16x8 a1 = ldfrag(ms + arow + 16 * 136 + t * 32);
#pragma unroll
                for (int ni = 0; ni < 4; ++ni) {
                    acc2[0][ni] = MFMA(a0, w2f[ni][t], acc2[0][ni]);
                    acc2[1][ni] = MFMA(a1, w2f[ni][t], acc2[1][ni]);
                }
            }
            __builtin_amdgcn_s_setprio(0);
        }
        // ---- store node outputs ----
#pragma unroll
        for (int mi = 0; mi < 2; ++mi) {
#pragma unroll
            for (int ni = 0; ni < 4; ++ni) {
                const int col = wv * 64 + ni * 16 + llo;
                const float b = b2s[col];
#pragma unroll
                for (int r = 0; r < 4; ++r) {
                    const int row = mi * 16 + lhi * 4 + r;
                    const int i = n0 + row;
                    if (i < NN) out[(size_t)i * 131 + 3 + col] = acc2[mi][ni][r] + b;
                }
            }
        }
        // ---- coords epilogue ----
        {
            const int el = tid >> 2, c = tid & 3;
            const int i = n0 + el;
            if (c < 3 && i < NN) {
                float cc = out[(size_t)i * 131 + c];
                out[(size_t)i * 131 + c] =
                    nf[(size_t)i * 131 + c] + cc / fmaxf((float)cnt[i], 1.f);
            }
        }
    }
}

extern "C" void kernel_launch(void* const* d_in, const int* in_sizes, int n_in,
                              void* d_out, int out_size, void* d_ws, size_t ws_size,
                              hipStream_t stream) {
    const float* nf = (const float*)d_in[0];
    const int* ei = (const int*)d_in[1];
    const float* ef = (const float*)d_in[2];
    const float* We1 = (const float*)d_in[3];
    const float* be1 = (const float*)d_in[4];
    const float* We2 = (const float*)d_in[5];
    const float* be2 = (const float*)d_in[6];
    const float* Wc = (const float*)d_in[7];
    const float* bc = (const float*)d_in[8];
    const float* Wn1 = (const float*)d_in[9];
    const float* bn1 = (const float*)d_in[10];
    const float* Wn2 = (const float*)d_in[11];
    const float* bn2 = (const float*)d_in[12];

    const int NN = in_sizes[0] / 131;
    const int NE = in_sizes[2] / 16;
    float* out = (float*)d_out;
    char* ws = (char*)d_ws;

    // ws layout: [cnt][cursor][bsum pad][sorted][hbf]
    const size_t szN = (size_t)NN * 4;
    const size_t o_cnt = 0;
    const size_t o_cur = szN;
    const size_t o_bsum = 2 * szN;
    const size_t o_sorted = (2 * szN + 4096 + 15) & ~(size_t)15;
    const size_t o_hbf_s = o_sorted + (size_t)NE * 16;
    const size_t need_core = o_hbf_s;
    const size_t need_full = o_hbf_s + (size_t)NN * 256;

    hipMemsetAsync(d_out, 0, (size_t)out_size * 4, stream);
    hipMemsetAsync(ws + o_cnt, 0, szN, stream);

    int* cnt = (int*)(ws + o_cnt);
    const int ntiles_n = (NN + 31) / 32;

    if (ws_size >= need_core) {
        int* cursor = (int*)(ws + o_cur);
        int* bsum = (int*)(ws + o_bsum);
        int4* sorted = (int4*)(ws + o_sorted);
        const bool use_hbf = ws_size >= need_full;
        u16* hbf = (u16*)(ws + o_hbf_s);

        if (use_hbf) k_prep<<<(NN * 16 + 255) / 256, 256, 0, stream>>>(nf, hbf, NN);
        k_hist<<<(NE + 255) / 256, 256, 0, stream>>>(ei, cnt, NE);
        const int NB = (NN + 1023) / 1024;
        k_scanA<<<NB, 256, 0, stream>>>(cnt, cursor, bsum, NN);
        k_scanB<<<1, 64, 0, stream>>>(bsum, NB);
        k_scanC<<<(NN + 255) / 256, 256, 0, stream>>>(cursor, bsum, NN);
        k_scatter<<<(NE + 255) / 256, 256, 0, stream>>>(ei, ei + NE, cursor, sorted, NE);

        const int ntiles_e = (NE + 31) / 32;
        if (use_hbf) {
            k_edge_s<1><<<1024, 128, 0, stream>>>(hbf, nf, sorted, ef,
                                                  We1, be1, We2, be2, Wc, bc, out, NE, ntiles_e);
            k_node<1><<<1024, 128, 0, stream>>>(hbf, nf, cnt, Wn1, bn1, Wn2, bn2, out, NN, ntiles_n);
        } else {
            k_edge_s<0><<<1024, 128, 0, stream>>>(hbf, nf, sorted, ef,
                                                  We1, be1, We2, be2, Wc, bc, out, NE, ntiles_e);
            k_node<0><<<1024, 128, 0, stream>>>(hbf, nf, cnt, Wn1, bn1, Wn2, bn2, out, NN, ntiles_n);
        }
    } else {
        // fallback: unsorted path (cnt + optional hbf)
        u16* hbf = (u16*)(ws + szN);
        const bool use_hbf = ws_size >= szN + (size_t)NN * 256;
        if (use_hbf) k_prep<<<(NN * 16 + 255) / 256, 256, 0, stream>>>(nf, hbf, NN);
        k_hist<<<(NE + 255) / 256, 256, 0, stream>>>(ei, cnt, NE);
        const int etiles = (NE + 63) / 64;
        if (use_hbf) {
            k_edge_u<1><<<512, 256, 0, stream>>>(hbf, nf, ei, ei + NE, ef,
                                                 We1, be1, We2, be2, Wc, bc, out, NE, etiles);
            k_node<1><<<1024, 128, 0, stream>>>(hbf, nf, cnt, Wn1, bn1, Wn2, bn2, out, NN, ntiles_n);
        } else {
            k_edge_u<0><<<512, 256, 0, stream>>>(hbf, nf, ei, ei + NE, ef,
                                                 We1, be1, We2, be2, Wc, bc, out, NE, etiles);
            k_node<0><<<1024, 128, 0, stream>>>(hbf, nf, cnt, Wn1, bn1, Wn2, bn2, out, NN, ntiles_n);
        }
    }
}